// Round 2
// baseline (4593.157 us; speedup 1.0000x reference)
//
#include <hip/hip_runtime.h>

// DubinsLSTM: 2-layer LSTM (H=128) over T=200 steps, B=1024, teacher forcing.
// Persistent kernel: each block owns EPB=4 batch elements for all T steps.
// R2: weights repacked transposed (column-major) into d_ws once per launch ->
// K-loop uses global_load_dwordx4 with immediate offsets instead of 384
// stride-2KB scalar loads per thread per step.

#define BB 1024
#define TT 200
#define INDIM 3
#define CDIM 4
#define HH 128
#define OD 3
#define GG 512   // 4*H
#define EPB 4    // batch elements per block

// d_ws layout (floats):
//   wt0 [512][128]  : Whh0^T          (offset 0)
//   wt1 [512][256]  : [Wih1;Whh1]^T   (offset 65536)
#define WT0_OFF 0
#define WT1_OFF 65536
#define WT_TOTAL (65536 + 131072)   // 196608 floats = 768 KB

__device__ __forceinline__ float sigf(float x) {
    return __fdividef(1.f, 1.f + __expf(-x));
}
// safe fast tanh: 1 - 2/(e^{2x}+1); handles +-inf correctly
__device__ __forceinline__ float tanhfast(float x) {
    return 1.f - __fdividef(2.f, __expf(2.f * x) + 1.f);
}

__global__ void repack_kernel(const float* __restrict__ Whh0,
                              const float* __restrict__ Wih1,
                              const float* __restrict__ Whh1,
                              float* __restrict__ wt) {
    int idx = blockIdx.x * 256 + threadIdx.x;   // 0 .. 196608
    if (idx < 65536) {                          // Whh0 [128][512] -> wt0[j][k]
        int k = idx >> 9, j = idx & 511;
        wt[WT0_OFF + j * HH + k] = Whh0[idx];
        return;
    }
    idx -= 65536;
    if (idx < 65536) {                          // Wih1 -> wt1[j][0..127]
        int k = idx >> 9, j = idx & 511;
        wt[WT1_OFF + j * 256 + k] = Wih1[idx];
        return;
    }
    idx -= 65536;
    {                                           // Whh1 -> wt1[j][128..255]
        int k = idx >> 9, j = idx & 511;
        wt[WT1_OFF + j * 256 + HH + k] = Whh1[idx];
    }
}

__global__ __launch_bounds__(512, 2) void dubins_lstm_kernel(
    const float* __restrict__ conds,       // [B,4]
    const float* __restrict__ target_seq,  // [B,T,3]
    const int*   __restrict__ lengths,     // [B]
    const float* __restrict__ tf_rand,     // [T,B]
    const float* __restrict__ Wc,          // [4,128]
    const float* __restrict__ bc,          // [128]
    const float* __restrict__ Wih0,        // [131,512]
    const float* __restrict__ b0,          // [512]
    const float* __restrict__ b1,          // [512]
    const float* __restrict__ Wo,          // [128,3]
    const float* __restrict__ bo,          // [3]
    const float* __restrict__ wt,          // repacked transposed weights
    float* __restrict__ out)               // [B,T,3]
{
    __shared__ float zb[EPB][GG];     // 8KB: gate pre-activations (reused L0/L1)
    __shared__ float h0s[EPB][HH];    // 2KB
    __shared__ float h1s[EPB][HH];    // 2KB
    __shared__ float prevs[EPB][4];   // prev autoregressive input (pad to 4)

    const int tid = threadIdx.x;
    const int b_base = blockIdx.x * EPB;
    const int j  = tid;        // gate-column owner role, j in [0,512)
    const int ge = tid >> 7;   // gate-update role: element
    const int gj = tid & 127;  // gate-update role: hidden unit

    // ---- init state ----
    h0s[ge][gj] = 0.f;
    h1s[ge][gj] = 0.f;
    if (tid < EPB * INDIM) prevs[tid / INDIM][tid % INDIM] = 0.f;

    // ---- cond_embed -> zb[e][0..127] (temp use of zb) ----
    {
        float v = bc[gj];
        #pragma unroll
        for (int k = 0; k < CDIM; ++k)
            v += conds[(b_base + ge) * CDIM + k] * Wc[k * HH + gj];
        zb[ge][gj] = v;
    }
    __syncthreads();

    // ---- time-invariant z0 part: cembz[e] = b0[j] + cemb[e,:] @ Wih0[3:,:j] ----
    float cembz[EPB];
    {
        const float bj = b0[j];
        #pragma unroll
        for (int e = 0; e < EPB; ++e) cembz[e] = bj;
        #pragma unroll 4
        for (int k = 0; k < HH; ++k) {
            const float w = Wih0[(INDIM + k) * GG + j];
            #pragma unroll
            for (int e = 0; e < EPB; ++e) cembz[e] += zb[e][k] * w;
        }
    }
    const float b1j = b1[j];
    // prev-input weight rows (time-invariant, 3 scalars)
    const float wp0 = Wih0[0 * GG + j];
    const float wp1 = Wih0[1 * GG + j];
    const float wp2 = Wih0[2 * GG + j];

    // ---- output-phase role ----
    const int pp = tid >> 5;            // 32-lane group id
    const int pl = tid & 31;
    const int pe = pp / OD;             // element (valid if pp<12)
    const int pd = pp - pe * OD;        // out dim
    const bool predrole = (pp < EPB * OD);
    int plen = 0; float pbo = 0.f;
    float wo[4] = {0.f, 0.f, 0.f, 0.f};
    if (predrole) {
        plen = lengths[b_base + pe];
        pbo = bo[pd];
        #pragma unroll
        for (int kk = 0; kk < 4; ++kk) wo[kk] = Wo[(pl + kk * 32) * OD + pd];
    }

    // transposed weight bases for this column
    const float4* __restrict__ w0c = reinterpret_cast<const float4*>(wt + WT0_OFF + j * HH);
    const float4* __restrict__ w1c = reinterpret_cast<const float4*>(wt + WT1_OFF + j * 256);

    float c0 = 0.f, c1 = 0.f;
    __syncthreads();   // zb temp reads done before step-0 overwrites

    for (int t = 0; t < TT; ++t) {
        float acc[EPB];

        // ========== layer-0 pre-activations ==========
        #pragma unroll
        for (int e = 0; e < EPB; ++e) {
            const float4 pv = *reinterpret_cast<const float4*>(&prevs[e][0]);
            acc[e] = fmaf(pv.z, wp2, fmaf(pv.y, wp1, fmaf(pv.x, wp0, cembz[e])));
        }
        {
            const float4* h4 = reinterpret_cast<const float4*>(&h0s[0][0]);
            #pragma unroll 8
            for (int kc = 0; kc < HH / 4; ++kc) {
                const float4 w = w0c[kc];
                #pragma unroll
                for (int e = 0; e < EPB; ++e) {
                    const float4 hv = h4[e * (HH / 4) + kc];
                    acc[e] = fmaf(hv.w, w.w, fmaf(hv.z, w.z,
                             fmaf(hv.y, w.y, fmaf(hv.x, w.x, acc[e]))));
                }
            }
        }
        #pragma unroll
        for (int e = 0; e < EPB; ++e) zb[e][j] = acc[e];
        __syncthreads();   // bar1: z0 ready

        // ========== layer-0 gate update ==========
        {
            const float zi = zb[ge][gj];
            const float zf = zb[ge][gj + HH];
            const float zg = zb[ge][gj + 2 * HH];
            const float zo = zb[ge][gj + 3 * HH];
            c0 = sigf(zf) * c0 + sigf(zi) * tanhfast(zg);
            h0s[ge][gj] = sigf(zo) * tanhfast(c0);
        }
        __syncthreads();   // bar2: h0 ready

        // ========== layer-1 pre-activations ==========
        #pragma unroll
        for (int e = 0; e < EPB; ++e) acc[e] = b1j;
        {
            const float4* h4 = reinterpret_cast<const float4*>(&h0s[0][0]);
            #pragma unroll 8
            for (int kc = 0; kc < HH / 4; ++kc) {
                const float4 w = w1c[kc];
                #pragma unroll
                for (int e = 0; e < EPB; ++e) {
                    const float4 hv = h4[e * (HH / 4) + kc];
                    acc[e] = fmaf(hv.w, w.w, fmaf(hv.z, w.z,
                             fmaf(hv.y, w.y, fmaf(hv.x, w.x, acc[e]))));
                }
            }
            const float4* g4 = reinterpret_cast<const float4*>(&h1s[0][0]);
            #pragma unroll 8
            for (int kc = 0; kc < HH / 4; ++kc) {
                const float4 w = w1c[HH / 4 + kc];
                #pragma unroll
                for (int e = 0; e < EPB; ++e) {
                    const float4 hv = g4[e * (HH / 4) + kc];
                    acc[e] = fmaf(hv.w, w.w, fmaf(hv.z, w.z,
                             fmaf(hv.y, w.y, fmaf(hv.x, w.x, acc[e]))));
                }
            }
        }
        #pragma unroll
        for (int e = 0; e < EPB; ++e) zb[e][j] = acc[e];
        __syncthreads();   // bar3: z1 ready

        // ========== layer-1 gate update ==========
        {
            const float zi = zb[ge][gj];
            const float zf = zb[ge][gj + HH];
            const float zg = zb[ge][gj + 2 * HH];
            const float zo = zb[ge][gj + 3 * HH];
            c1 = sigf(zf) * c1 + sigf(zi) * tanhfast(zg);
            h1s[ge][gj] = sigf(zo) * tanhfast(c1);
        }
        __syncthreads();   // bar4: h1 ready

        // ========== output projection + teacher forcing ==========
        if (predrole) {
            float part = 0.f;
            #pragma unroll
            for (int kk = 0; kk < 4; ++kk) {
                part = fmaf(h1s[pe][pl + kk * 32], wo[kk], part);
            }
            part += __shfl_xor(part, 16, 32);
            part += __shfl_xor(part, 8, 32);
            part += __shfl_xor(part, 4, 32);
            part += __shfl_xor(part, 2, 32);
            part += __shfl_xor(part, 1, 32);
            if (pl == 0) {
                const float pred = part + pbo;
                const int bg = b_base + pe;
                out[(bg * TT + t) * OD + pd] = pred;
                const bool use_tf = (tf_rand[t * BB + bg] < 0.5f) && (t < plen);
                prevs[pe][pd] = use_tf ? target_seq[(bg * TT + t) * OD + pd] : pred;
            }
        }
        __syncthreads();   // bar5: prev ready for next step
    }
}

extern "C" void kernel_launch(void* const* d_in, const int* in_sizes, int n_in,
                              void* d_out, int out_size, void* d_ws, size_t ws_size,
                              hipStream_t stream) {
    const float* conds   = (const float*)d_in[0];
    const float* target  = (const float*)d_in[1];
    const int*   lengths = (const int*)d_in[2];
    const float* tfr     = (const float*)d_in[3];
    const float* Wc      = (const float*)d_in[4];
    const float* bc      = (const float*)d_in[5];
    const float* Wih0    = (const float*)d_in[6];
    const float* Whh0    = (const float*)d_in[7];
    const float* b0      = (const float*)d_in[8];
    const float* Wih1    = (const float*)d_in[9];
    const float* Whh1    = (const float*)d_in[10];
    const float* b1      = (const float*)d_in[11];
    const float* Wo      = (const float*)d_in[12];
    const float* bo      = (const float*)d_in[13];
    float* out = (float*)d_out;
    float* wt  = (float*)d_ws;

    repack_kernel<<<WT_TOTAL / 256, 256, 0, stream>>>(Whh0, Wih1, Whh1, wt);
    dubins_lstm_kernel<<<BB / EPB, 512, 0, stream>>>(
        conds, target, lengths, tfr, Wc, bc,
        Wih0, b0, b1, Wo, bo, wt, out);
}

// Round 3
// 1280.988 us; speedup vs baseline: 3.5856x; 3.5856x over previous
//
#include <hip/hip_runtime.h>

// DubinsLSTM: 2-layer LSTM (H=128) over T=200 steps, B=1024, teacher forcing.
// Persistent kernel: each block owns EPB=4 batch elements for all T steps.
// R3: recurrent weights repacked to f16 in [K/8][512][8] layout (coalesced
// uint4 loads, 8 k-values per column per load); h stored as packed f16 pairs
// in LDS; inner product via v_dot2_f32_f16 (2 MACs/instr, f32 accumulate).
// L2 weight stream halves vs fp32 -> floor ~590us.

#define BB 1024
#define TT 200
#define INDIM 3
#define CDIM 4
#define HH 128
#define OD 3
#define GG 512   // 4*H
#define EPB 4    // batch elements per block

// d_ws layout (halves):
//   hw0 [16][512][8]  : Whh0 f16, chunked-8 by k      (offset 0, 65536 halves)
//   hw1 [32][512][8]  : [Wih1;Whh1] f16, chunked-8    (offset 65536, 131072 halves)
#define HW1_OFF 65536
#define HW_TOTAL_ELEMS 196608   // halves (393216 B)

typedef _Float16 half2v __attribute__((ext_vector_type(2)));

__device__ __forceinline__ float sigf(float x) {
    return __fdividef(1.f, 1.f + __expf(-x));
}
// safe fast tanh: 1 - 2/(e^{2x}+1); handles +-inf correctly
__device__ __forceinline__ float tanhfast(float x) {
    return 1.f - __fdividef(2.f, __expf(2.f * x) + 1.f);
}

__device__ __forceinline__ float dot2acc(uint32_t hp_, uint32_t wp_, float acc) {
    half2v a = __builtin_bit_cast(half2v, hp_);
    half2v b = __builtin_bit_cast(half2v, wp_);
#if __has_builtin(__builtin_amdgcn_fdot2)
    return __builtin_amdgcn_fdot2(a, b, acc, false);
#else
    acc = fmaf((float)a.x, (float)b.x, acc);
    return fmaf((float)a.y, (float)b.y, acc);
#endif
}

__device__ __forceinline__ uint32_t pack2(float lo, float hi) {
    half2v v;
    v.x = (_Float16)lo;
    v.y = (_Float16)hi;
    return __builtin_bit_cast(uint32_t, v);
}

__global__ void repack_f16_kernel(const float* __restrict__ Whh0,
                                  const float* __restrict__ Wih1,
                                  const float* __restrict__ Whh1,
                                  _Float16* __restrict__ hw) {
    int idx = blockIdx.x * 256 + threadIdx.x;   // 0 .. 196608
    if (idx < 65536) {                          // Whh0 [128][512]
        int k = idx >> 9, j = idx & 511;
        hw[((((k >> 3) << 9) + j) << 3) + (k & 7)] = (_Float16)Whh0[idx];
        return;
    }
    idx -= 65536;
    if (idx < 65536) {                          // Wih1 [128][512] -> k' = k
        int k = idx >> 9, j = idx & 511;
        hw[HW1_OFF + (((((k >> 3) << 9) + j) << 3) + (k & 7))] = (_Float16)Wih1[idx];
        return;
    }
    idx -= 65536;
    {                                           // Whh1 [128][512] -> k' = 128+k
        int k = (idx >> 9) + 128, j = idx & 511;
        hw[HW1_OFF + (((((k >> 3) << 9) + j) << 3) + (k & 7))] = (_Float16)Whh1[idx];
    }
}

__global__ __launch_bounds__(512, 2) void dubins_lstm_kernel(
    const float* __restrict__ conds,       // [B,4]
    const float* __restrict__ target_seq,  // [B,T,3]
    const int*   __restrict__ lengths,     // [B]
    const float* __restrict__ tf_rand,     // [T,B]
    const float* __restrict__ Wc,          // [4,128]
    const float* __restrict__ bc,          // [128]
    const float* __restrict__ Wih0,        // [131,512] (fp32, used once)
    const float* __restrict__ b0,          // [512]
    const float* __restrict__ b1,          // [512]
    const float* __restrict__ Wo,          // [128,3]
    const float* __restrict__ bo,          // [3]
    const _Float16* __restrict__ hw,       // repacked f16 weights
    float* __restrict__ out)               // [B,T,3]
{
    __shared__ float zb[EPB][GG];        // 8KB: gate pre-activations
    __shared__ uint32_t hp[EPB * 128];   // 2KB: packed f16 pairs: [0..63]=h0, [64..127]=h1
    __shared__ float h1s[EPB][HH];       // 2KB: f32 h1 for output projection
    __shared__ float prevs[EPB][4];      // prev autoregressive input (pad to 4)

    const int tid = threadIdx.x;
    const int b_base = blockIdx.x * EPB;
    const int j  = tid;        // gate-column owner role, j in [0,512)
    const int ge = tid >> 7;   // gate-update role: element
    const int gj = tid & 127;  // gate-update role: hidden unit

    // ---- init state ----
    hp[tid] = 0u;              // h0,h1 = 0 (512 words = EPB*128)
    h1s[ge][gj] = 0.f;
    if (tid < EPB * INDIM) prevs[tid / INDIM][tid % INDIM] = 0.f;

    // ---- cond_embed -> zb[e][0..127] (temp use of zb) ----
    {
        float v = bc[gj];
        #pragma unroll
        for (int k = 0; k < CDIM; ++k)
            v += conds[(b_base + ge) * CDIM + k] * Wc[k * HH + gj];
        zb[ge][gj] = v;
    }
    __syncthreads();

    // ---- time-invariant z0 part: cembz[e] = b0[j] + cemb[e,:] @ Wih0[3:,:j] ----
    float cembz[EPB];
    {
        const float bj = b0[j];
        #pragma unroll
        for (int e = 0; e < EPB; ++e) cembz[e] = bj;
        #pragma unroll 4
        for (int k = 0; k < HH; ++k) {
            const float w = Wih0[(INDIM + k) * GG + j];
            #pragma unroll
            for (int e = 0; e < EPB; ++e) cembz[e] += zb[e][k] * w;
        }
    }
    const float b1j = b1[j];
    // prev-input weight rows (time-invariant, 3 scalars, fp32)
    const float wp0 = Wih0[0 * GG + j];
    const float wp1 = Wih0[1 * GG + j];
    const float wp2 = Wih0[2 * GG + j];

    // ---- output-phase role ----
    const int pp = tid >> 5;            // 32-lane group id
    const int pl = tid & 31;
    const int pe = pp / OD;             // element (valid if pp<12)
    const int pd = pp - pe * OD;        // out dim
    const bool predrole = (pp < EPB * OD);
    int plen = 0; float pbo = 0.f;
    float wo[4] = {0.f, 0.f, 0.f, 0.f};
    if (predrole) {
        plen = lengths[b_base + pe];
        pbo = bo[pd];
        #pragma unroll
        for (int kk = 0; kk < 4; ++kk) wo[kk] = Wo[(pl + kk * 32) * OD + pd];
    }

    // weight bases: chunked-8 f16 layout, lane-adjacent -> coalesced uint4
    const uint4* __restrict__ w0 = reinterpret_cast<const uint4*>(hw) + j;            // [16][512]
    const uint4* __restrict__ w1 = reinterpret_cast<const uint4*>(hw + HW1_OFF) + j;  // [32][512]
    const uint4* hp4 = reinterpret_cast<const uint4*>(hp);  // [EPB][32]

    float c0 = 0.f, c1 = 0.f;
    __syncthreads();   // zb temp reads + hp init done

    for (int t = 0; t < TT; ++t) {
        float acc[EPB];

        // ========== layer-0 pre-activations:  z0 = cembz + prev@Wih0[0:3] + h0@Whh0 ==========
        #pragma unroll
        for (int e = 0; e < EPB; ++e) {
            const float4 pv = *reinterpret_cast<const float4*>(&prevs[e][0]);
            acc[e] = fmaf(pv.z, wp2, fmaf(pv.y, wp1, fmaf(pv.x, wp0, cembz[e])));
        }
        #pragma unroll 4
        for (int kc = 0; kc < 16; ++kc) {
            const uint4 w8 = w0[kc * 512];
            #pragma unroll
            for (int e = 0; e < EPB; ++e) {
                const uint4 h8 = hp4[e * 32 + kc];
                acc[e] = dot2acc(h8.x, w8.x, acc[e]);
                acc[e] = dot2acc(h8.y, w8.y, acc[e]);
                acc[e] = dot2acc(h8.z, w8.z, acc[e]);
                acc[e] = dot2acc(h8.w, w8.w, acc[e]);
            }
        }
        #pragma unroll
        for (int e = 0; e < EPB; ++e) zb[e][j] = acc[e];
        __syncthreads();   // bar1: z0 ready

        // ========== layer-0 gate update ==========
        {
            const float zi = zb[ge][gj];
            const float zf = zb[ge][gj + HH];
            const float zg = zb[ge][gj + 2 * HH];
            const float zo = zb[ge][gj + 3 * HH];
            c0 = sigf(zf) * c0 + sigf(zi) * tanhfast(zg);
            const float h = sigf(zo) * tanhfast(c0);
            const float hx = __shfl_xor(h, 1);
            if (!(gj & 1)) hp[ge * 128 + (gj >> 1)] = pack2(h, hx);
        }
        __syncthreads();   // bar2: h0 (packed) ready

        // ========== layer-1 pre-activations:  z1 = b1 + [h0;h1]@[Wih1;Whh1] ==========
        #pragma unroll
        for (int e = 0; e < EPB; ++e) acc[e] = b1j;
        #pragma unroll 4
        for (int kc = 0; kc < 32; ++kc) {
            const uint4 w8 = w1[kc * 512];
            #pragma unroll
            for (int e = 0; e < EPB; ++e) {
                const uint4 h8 = hp4[e * 32 + kc];   // kc<16: h0, kc>=16: h1 (prev step)
                acc[e] = dot2acc(h8.x, w8.x, acc[e]);
                acc[e] = dot2acc(h8.y, w8.y, acc[e]);
                acc[e] = dot2acc(h8.z, w8.z, acc[e]);
                acc[e] = dot2acc(h8.w, w8.w, acc[e]);
            }
        }
        #pragma unroll
        for (int e = 0; e < EPB; ++e) zb[e][j] = acc[e];
        __syncthreads();   // bar3: z1 ready (and old h1 fully consumed)

        // ========== layer-1 gate update ==========
        {
            const float zi = zb[ge][gj];
            const float zf = zb[ge][gj + HH];
            const float zg = zb[ge][gj + 2 * HH];
            const float zo = zb[ge][gj + 3 * HH];
            c1 = sigf(zf) * c1 + sigf(zi) * tanhfast(zg);
            const float h = sigf(zo) * tanhfast(c1);
            h1s[ge][gj] = h;
            const float hx = __shfl_xor(h, 1);
            if (!(gj & 1)) hp[ge * 128 + 64 + (gj >> 1)] = pack2(h, hx);
        }
        __syncthreads();   // bar4: h1 ready

        // ========== output projection + teacher forcing ==========
        if (predrole) {
            float part = 0.f;
            #pragma unroll
            for (int kk = 0; kk < 4; ++kk) {
                part = fmaf(h1s[pe][pl + kk * 32], wo[kk], part);
            }
            part += __shfl_xor(part, 16, 32);
            part += __shfl_xor(part, 8, 32);
            part += __shfl_xor(part, 4, 32);
            part += __shfl_xor(part, 2, 32);
            part += __shfl_xor(part, 1, 32);
            if (pl == 0) {
                const float pred = part + pbo;
                const int bg = b_base + pe;
                out[(bg * TT + t) * OD + pd] = pred;
                const bool use_tf = (tf_rand[t * BB + bg] < 0.5f) && (t < plen);
                prevs[pe][pd] = use_tf ? target_seq[(bg * TT + t) * OD + pd] : pred;
            }
        }
        __syncthreads();   // bar5: prev ready for next step
    }
}

extern "C" void kernel_launch(void* const* d_in, const int* in_sizes, int n_in,
                              void* d_out, int out_size, void* d_ws, size_t ws_size,
                              hipStream_t stream) {
    const float* conds   = (const float*)d_in[0];
    const float* target  = (const float*)d_in[1];
    const int*   lengths = (const int*)d_in[2];
    const float* tfr     = (const float*)d_in[3];
    const float* Wc      = (const float*)d_in[4];
    const float* bc      = (const float*)d_in[5];
    const float* Wih0    = (const float*)d_in[6];
    const float* Whh0    = (const float*)d_in[7];
    const float* b0      = (const float*)d_in[8];
    const float* Wih1    = (const float*)d_in[9];
    const float* Whh1    = (const float*)d_in[10];
    const float* b1      = (const float*)d_in[11];
    const float* Wo      = (const float*)d_in[12];
    const float* bo      = (const float*)d_in[13];
    float* out = (float*)d_out;
    _Float16* hw = (_Float16*)d_ws;

    repack_f16_kernel<<<HW_TOTAL_ELEMS / 256, 256, 0, stream>>>(Whh0, Wih1, Whh1, hw);
    dubins_lstm_kernel<<<BB / EPB, 512, 0, stream>>>(
        conds, target, lengths, tfr, Wc, bc,
        Wih0, b0, b1, Wo, bo, hw, out);
}